// Round 5
// baseline (636.249 us; speedup 1.0000x reference)
//
#include <hip/hip_runtime.h>
#include <hip/hip_bf16.h>
#include <stdint.h>

using bf16 = __hip_bfloat16;
typedef short bf16x8 __attribute__((ext_vector_type(8)));
typedef float floatx4 __attribute__((ext_vector_type(4)));

static constexpr int NODES = 2048;
static constexpr int EDGES = 32768;

// pack 8 consecutive f32 -> 8 bf16 (rne) as uint4
__device__ inline uint4 cvt8(const float* __restrict__ p) {
    const float4* f = (const float4*)p;
    float4 a = f[0], b = f[1];
    union { uint4 u; bf16 h[8]; } pk;
    pk.h[0] = __float2bfloat16(a.x); pk.h[1] = __float2bfloat16(a.y);
    pk.h[2] = __float2bfloat16(a.z); pk.h[3] = __float2bfloat16(a.w);
    pk.h[4] = __float2bfloat16(b.x); pk.h[5] = __float2bfloat16(b.y);
    pk.h[6] = __float2bfloat16(b.z); pk.h[7] = __float2bfloat16(b.w);
    return pk.u;
}

// ---------------- zero agg (2 MB) + cnt (8 KB) ----------------
__global__ __launch_bounds__(256) void zero_all(float4* __restrict__ agg,
                                                int4* __restrict__ cnt) {
    if (blockIdx.x < 512) {
        agg[(size_t)blockIdx.x * 256 + threadIdx.x] = float4{0.f, 0.f, 0.f, 0.f};
    } else {
        cnt[threadIdx.x * 2]     = int4{0, 0, 0, 0};
        cnt[threadIdx.x * 2 + 1] = int4{0, 0, 0, 0};
    }
}

// ---------------- index extraction from f32 one-hot rows ----------------
// one wave per row; up to 8 coalesced uint4 passes, wave-level early exit.
__global__ __launch_bounds__(256) void extract_idx(
    const float* __restrict__ rel_rec, const float* __restrict__ rel_send,
    int* __restrict__ recv_idx, int* __restrict__ send_idx)
{
    const int b = blockIdx.x;          // 0..16383
    const int half = b >> 13;          // 0: rel_rec, 1: rel_send
    const int rb = b & 8191;
    const float* mat = half ? rel_send : rel_rec;
    int* out = half ? send_idx : recv_idx;
    const int w = threadIdx.x >> 6;
    const int lane = threadIdx.x & 63;
    const int row = rb * 4 + w;        // 0..32767
    if (lane == 0) out[row] = 0;       // defensive init
    const uint4* base = (const uint4*)(mat + (size_t)row * NODES);
    for (int p = 0; p < 8; ++p) {
        uint4 v = base[p * 64 + lane];
        const bool hit = (v.x | v.y | v.z | v.w) != 0u;
        if (hit) {
            int e = v.x ? 0 : (v.y ? 1 : (v.z ? 2 : 3));
            out[row] = p * 256 + lane * 4 + e;
        }
        if (__any(hit)) break;
    }
}

// ---------------- counting sort of edges by receiver ----------------
__global__ __launch_bounds__(256) void hist_recv(const int* __restrict__ recv_idx,
                                                 int* __restrict__ cnt) {
    const int e = blockIdx.x * 256 + threadIdx.x;
    atomicAdd(&cnt[recv_idx[e] & (NODES - 1)], 1);
}

// exclusive prefix sum over 2048 counters, single block of 256 threads
__global__ __launch_bounds__(256) void scan_offsets(const int* __restrict__ cnt,
                                                    int* __restrict__ cur) {
    __shared__ int part[256];
    const int t = threadIdx.x;
    int loc[8];
    int s = 0;
#pragma unroll
    for (int i = 0; i < 8; ++i) { loc[i] = s; s += cnt[t * 8 + i]; }
    part[t] = s;
    __syncthreads();
    if (t == 0) {
        int acc = 0;
        for (int i = 0; i < 256; ++i) { int v = part[i]; part[i] = acc; acc += v; }
    }
    __syncthreads();
    const int b = part[t];
#pragma unroll
    for (int i = 0; i < 8; ++i) cur[t * 8 + i] = b + loc[i];
}

__global__ __launch_bounds__(256) void scatter_perm(const int* __restrict__ recv_idx,
                                                    int* __restrict__ cur,
                                                    int* __restrict__ perm) {
    const int e = blockIdx.x * 256 + threadIdx.x;
    const int slot = atomicAdd(&cur[recv_idx[e] & (NODES - 1)], 1);
    perm[slot & (EDGES - 1)] = e;
}

// ---------------- generic 128x128 MFMA GEMM (bf16 MFMA core) ---------------
// C[m,n] = epilogue( sum_k A[m,k] * B'[n,k] + bias[n] )
// AMODE 0: A bf16 scratch [M,K]
// AMODE 1: A f32 [M,K] (cvt in staging)
// AMODE 2: A row n = concat(inputsF[n], aggin[n]) f32->bf16 (K=512)
// AMODE 3: A row s (receiver-sorted slot, e=perm[s]) =
//          relu(U[send[e]][k] + V[recv[e]][k] + b1[k]) f32->bf16 (K=512)
// BMODE 0: B' = Bt f32 [N,K]
// BMODE 1: B' row n = msg_W1[n&511][ (n>>9)*256 .. +K ]  (split W1 halves)
// EPI 0: +bias, relu, store bf16 Cout[M,N]
// EPI 1: +bias, relu, run-compressed atomicAdd into aggout[rIdx[row]*256+n]
// EPI 2: +bias, add f32 residual inputsF[m,n], store f32 OutF (N==256)
// EPI 3: raw f32 store OutF[M,N] (no bias)
template<int AMODE, int BMODE, int EPI>
__global__ __launch_bounds__(256, 2) void gemm128(
    const bf16* __restrict__ A, const float* __restrict__ Af,
    const float* __restrict__ Bt, const float* __restrict__ bias,
    bf16* __restrict__ Cout, float* __restrict__ OutF,
    const float* __restrict__ inputsF, const float* __restrict__ UV,
    const float* __restrict__ b1v, const int* __restrict__ sidx,
    const int* __restrict__ ridx, const int* __restrict__ perm,
    const float* __restrict__ aggin, float* __restrict__ aggout,
    int M, int N, int K)
{
    constexpr int BM = 128, BN = 128, BK = 32;
    __shared__ bf16 As[BM * BK];   // 8 KB
    __shared__ bf16 Bs[BN * BK];   // 8 KB
    __shared__ int sIdx[BM];
    __shared__ int rIdx[BM];

    const int t = threadIdx.x;
    const int m0 = blockIdx.y * BM;
    const int n0 = blockIdx.x * BN;

    if constexpr (AMODE == 3) {
        if (t < BM) {
            const int pe = perm[m0 + t] & (EDGES - 1);
            sIdx[t] = sidx[pe] & (NODES - 1);
            rIdx[t] = ridx[pe] & (NODES - 1);   // sorted: long runs of equal values
        }
        __syncthreads();
    }

    // staging: thread t covers LDS row (p*64 + t/4), 16B bf16 chunk (t%4)
    const int sr = t >> 2;
    const int sc = t & 3;

    uint4 ra[2], rb[2];

    auto loadTiles = [&](int kt) {
        const int kk = kt * BK + sc * 8;   // element column within K
#pragma unroll
        for (int p = 0; p < 2; ++p) {
            const int row = p * 64 + sr;
            if constexpr (AMODE == 0) {
                ra[p] = *(const uint4*)(A + (size_t)(m0 + row) * K + kk);
            } else if constexpr (AMODE == 1) {
                ra[p] = cvt8(Af + (size_t)(m0 + row) * K + kk);
            } else if constexpr (AMODE == 2) {
                const float* src = (kk < 256)
                    ? (inputsF + (size_t)(m0 + row) * 256 + kk)
                    : (aggin + (size_t)(m0 + row) * 256 + (kk - 256));
                ra[p] = cvt8(src);
            } else {
                const float4* u = (const float4*)(UV + (size_t)sIdx[row] * 1024 + kk);
                const float4* v = (const float4*)(UV + (size_t)rIdx[row] * 1024 + 512 + kk);
                const float4* c = (const float4*)(b1v + kk);
                float4 u0 = u[0], u1 = u[1], v0 = v[0], v1 = v[1], c0 = c[0], c1 = c[1];
                union { uint4 q; bf16 h[8]; } pk;
                pk.h[0] = __float2bfloat16(fmaxf(u0.x + v0.x + c0.x, 0.f));
                pk.h[1] = __float2bfloat16(fmaxf(u0.y + v0.y + c0.y, 0.f));
                pk.h[2] = __float2bfloat16(fmaxf(u0.z + v0.z + c0.z, 0.f));
                pk.h[3] = __float2bfloat16(fmaxf(u0.w + v0.w + c0.w, 0.f));
                pk.h[4] = __float2bfloat16(fmaxf(u1.x + v1.x + c1.x, 0.f));
                pk.h[5] = __float2bfloat16(fmaxf(u1.y + v1.y + c1.y, 0.f));
                pk.h[6] = __float2bfloat16(fmaxf(u1.z + v1.z + c1.z, 0.f));
                pk.h[7] = __float2bfloat16(fmaxf(u1.w + v1.w + c1.w, 0.f));
                ra[p] = pk.q;
            }
            if constexpr (BMODE == 0) {
                rb[p] = cvt8(Bt + (size_t)(n0 + row) * K + kk);
            } else {
                const int n = n0 + row;
                rb[p] = cvt8(Bt + (size_t)(n & 511) * 512 + (n >> 9) * 256 + kk);
            }
        }
    };

    const int wv = t >> 6;
    const int lane = t & 63;
    const int wm = wv >> 1, wn = wv & 1;   // wave covers 64x64 region
    const int r16 = lane & 15, q = lane >> 4;

    floatx4 acc[4][4] = {};

    loadTiles(0);
    const int KT = K / BK;
    for (int kt = 0; kt < KT; ++kt) {
        __syncthreads();
#pragma unroll
        for (int p = 0; p < 2; ++p) {
            *(uint4*)(&As[(p * 64 + sr) * BK + sc * 8]) = ra[p];
            *(uint4*)(&Bs[(p * 64 + sr) * BK + sc * 8]) = rb[p];
        }
        __syncthreads();
        if (kt + 1 < KT) loadTiles(kt + 1);   // overlap next-tile loads with MFMA

        bf16x8 af[4], bfr[4];
#pragma unroll
        for (int i = 0; i < 4; ++i)
            af[i] = *(const bf16x8*)(&As[(wm * 64 + i * 16 + r16) * BK + q * 8]);
#pragma unroll
        for (int j = 0; j < 4; ++j)
            bfr[j] = *(const bf16x8*)(&Bs[(wn * 64 + j * 16 + r16) * BK + q * 8]);
#pragma unroll
        for (int i = 0; i < 4; ++i)
#pragma unroll
            for (int j = 0; j < 4; ++j)
                acc[i][j] = __builtin_amdgcn_mfma_f32_16x16x32_bf16(af[i], bfr[j], acc[i][j], 0, 0, 0);
    }

    float bv[4];
#pragma unroll
    for (int j = 0; j < 4; ++j)
        bv[j] = (EPI == 3) ? 0.f : bias[n0 + wn * 64 + j * 16 + r16];

    // C/D layout: col = lane&15, row = q*4 + r (verified m89/m91)
#pragma unroll
    for (int i = 0; i < 4; ++i) {
        const int lr = wm * 64 + i * 16 + q * 4;   // local row of first r
        const int rbase = m0 + lr;
#pragma unroll
        for (int j = 0; j < 4; ++j) {
            const int gc = n0 + wn * 64 + j * 16 + r16;
            if constexpr (EPI == 1) {
                // rows lr..lr+3 are consecutive receiver-sorted edges:
                // run-compress equal receivers -> ~4x fewer atomics
                int curR = rIdx[lr];
                float run = 0.f;
#pragma unroll
                for (int r = 0; r < 4; ++r) {
                    const float v = fmaxf(acc[i][j][r] + bv[j], 0.f);
                    const int rr = rIdx[lr + r];
                    if (rr != curR) {
                        atomicAdd(&aggout[(size_t)curR * 256 + gc], run);
                        curR = rr; run = v;
                    } else {
                        run += v;
                    }
                }
                atomicAdd(&aggout[(size_t)curR * 256 + gc], run);
            } else {
#pragma unroll
                for (int r = 0; r < 4; ++r) {
                    float v = acc[i][j][r] + bv[j];
                    const int gr = rbase + r;
                    if constexpr (EPI == 0) {
                        v = fmaxf(v, 0.0f);
                        Cout[(size_t)gr * N + gc] = __float2bfloat16(v);
                    } else if constexpr (EPI == 2) {
                        OutF[(size_t)gr * 256 + gc] = inputsF[(size_t)gr * 256 + gc] + v;
                    } else if constexpr (EPI == 3) {
                        OutF[(size_t)gr * N + gc] = v;
                    }
                }
            }
        }
    }
}

extern "C" void kernel_launch(void* const* d_in, const int* in_sizes, int n_in,
                              void* d_out, int out_size, void* d_ws, size_t ws_size,
                              hipStream_t stream) {
    const float* inputs   = (const float*)d_in[0];
    const float* rel_rec  = (const float*)d_in[1];
    const float* rel_send = (const float*)d_in[2];
    const float* msg_W1   = (const float*)d_in[3];
    const float* msg_b1   = (const float*)d_in[4];
    const float* msg_W2   = (const float*)d_in[5];
    const float* msg_b2   = (const float*)d_in[6];
    const float* out_W1   = (const float*)d_in[7];
    const float* out_b1   = (const float*)d_in[8];
    const float* out_W2   = (const float*)d_in[9];
    const float* out_b2   = (const float*)d_in[10];
    const float* out_W3   = (const float*)d_in[11];
    const float* out_b3   = (const float*)d_in[12];

    // workspace layout (~14.4 MB total)
    char* ws = (char*)d_ws;
    int*   recv_idx = (int*)(ws + 0);            // 128 KB
    int*   send_idx = (int*)(ws + 131072);       // 128 KB
    float* agg      = (float*)(ws + 262144);     // 2 MB fp32 [2048,256]
    float* UV       = (float*)(ws + 2359296);    // 8 MB fp32 [2048,1024] (U|V)
    bf16*  g1       = (bf16*)(ws + 10747904);    // 2 MB bf16 [2048,512]
    bf16*  g2       = (bf16*)(ws + 12845056);    // 2 MB bf16 [2048,512]
    int*   perm     = (int*)(ws + 14942208);     // 128 KB
    int*   cnt      = (int*)(ws + 15073280);     // 8 KB
    int*   cur      = (int*)(ws + 15081472);     // 8 KB
    if (ws_size < (size_t)16 * 1024 * 1024) return;  // fail loudly, not fault

    // 1) recover edge indices from f32 one-hot incidence matrices
    extract_idx<<<16384, 256, 0, stream>>>(rel_rec, rel_send, recv_idx, send_idx);

    // 2) zero agg + histogram counters
    zero_all<<<513, 256, 0, stream>>>((float4*)agg, (int4*)cnt);

    // 3) counting-sort edge ids by receiver -> perm
    hist_recv<<<EDGES / 256, 256, 0, stream>>>(recv_idx, cnt);
    scan_offsets<<<1, 256, 0, stream>>>(cnt, cur);
    scatter_perm<<<EDGES / 256, 256, 0, stream>>>(recv_idx, cur, perm);

    // 4) UV = inputs @ [W1_left | W1_right]^T  (node space, 1.07 GFLOP)
    gemm128<1, 1, 3><<<dim3(1024 / 128, NODES / 128), 256, 0, stream>>>(
        nullptr, inputs, msg_W1, nullptr, nullptr, UV,
        nullptr, nullptr, nullptr, nullptr, nullptr, nullptr, nullptr, nullptr,
        NODES, 1024, 256);

    // 5) fused edge layer-2 + sorted scatter:
    //    agg[recv[e]] += relu( relu(U[send[e]]+V[recv[e]]+b1) @ W2^T + b2 )
    gemm128<3, 0, 1><<<dim3(256 / 128, EDGES / 128), 256, 0, stream>>>(
        nullptr, nullptr, msg_W2, msg_b2, nullptr, nullptr,
        nullptr, UV, msg_b1, send_idx, recv_idx, perm, nullptr, agg,
        EDGES, 256, 512);

    // 6) node MLP layer 1: g1 = relu(concat(inputs, agg) @ out_W1^T + b1)
    gemm128<2, 0, 0><<<dim3(512 / 128, NODES / 128), 256, 0, stream>>>(
        nullptr, nullptr, out_W1, out_b1, g1, nullptr,
        inputs, nullptr, nullptr, nullptr, nullptr, nullptr, agg, nullptr,
        NODES, 512, 512);

    // 7) node MLP layer 2: g2 = relu(g1 @ out_W2^T + b2)
    gemm128<0, 0, 0><<<dim3(512 / 128, NODES / 128), 256, 0, stream>>>(
        g1, nullptr, out_W2, out_b2, g2, nullptr,
        nullptr, nullptr, nullptr, nullptr, nullptr, nullptr, nullptr, nullptr,
        NODES, 512, 512);

    // 8) node MLP layer 3 + residual: out = inputs + (g2 @ out_W3^T + b3)
    gemm128<0, 0, 2><<<dim3(256 / 128, NODES / 128), 256, 0, stream>>>(
        g2, nullptr, out_W3, out_b3, nullptr, (float*)d_out,
        inputs, nullptr, nullptr, nullptr, nullptr, nullptr, nullptr, nullptr,
        NODES, 256, 512);
}

// Round 6
// 602.635 us; speedup vs baseline: 1.0558x; 1.0558x over previous
//
#include <hip/hip_runtime.h>
#include <hip/hip_bf16.h>
#include <stdint.h>

using bf16 = __hip_bfloat16;
typedef short bf16x8 __attribute__((ext_vector_type(8)));
typedef float floatx4 __attribute__((ext_vector_type(4)));

static constexpr int NODES = 2048;
static constexpr int EDGES = 32768;

// pack 8 consecutive f32 -> 8 bf16 (rne) as uint4
__device__ inline uint4 cvt8(const float* __restrict__ p) {
    const float4* f = (const float4*)p;
    float4 a = f[0], b = f[1];
    union { uint4 u; bf16 h[8]; } pk;
    pk.h[0] = __float2bfloat16(a.x); pk.h[1] = __float2bfloat16(a.y);
    pk.h[2] = __float2bfloat16(a.z); pk.h[3] = __float2bfloat16(a.w);
    pk.h[4] = __float2bfloat16(b.x); pk.h[5] = __float2bfloat16(b.y);
    pk.h[6] = __float2bfloat16(b.z); pk.h[7] = __float2bfloat16(b.w);
    return pk.u;
}

// ---------------- generic BMxBN MFMA GEMM body (bf16 MFMA core) ------------
// C[m,n] = epilogue( sum_k A[m,k] * B'[n,k] + bias[n] )
// AMODE 0: A bf16 scratch [M,K]
// AMODE 1: A f32 [M,K] (cvt in staging)
// AMODE 2: A row n = concat(inputsF[n], aggin[n]) f32->bf16 (K=512)
// AMODE 3: A row e = relu(U[sidx[e]][k] + V[ridx[e]][k] + b1[k]) f32->bf16 (K=512)
// BMODE 0: B' = Bt f32 [N,K]
// BMODE 1: B' row n = msg_W1[n&511][ (n>>9)*256 .. +K ]  (split W1 halves)
// EPI 0: +bias, relu, store bf16 Cout[M,N]
// EPI 1: +bias, relu, atomicAdd fp32 into aggout[rIdx[row]*256+n]
// EPI 2: +bias, add f32 residual inputsF[m,n], store f32 OutF (N==256)
// EPI 3: raw f32 store OutF[M,N] (no bias)
template<int BM, int BN, int AMODE, int BMODE, int EPI>
__device__ __forceinline__ void gemm_body(
    const bf16* __restrict__ A, const float* __restrict__ Af,
    const float* __restrict__ Bt, const float* __restrict__ bias,
    bf16* __restrict__ Cout, float* __restrict__ OutF,
    const float* __restrict__ inputsF, const float* __restrict__ UV,
    const float* __restrict__ b1v, const int* __restrict__ sidx,
    const int* __restrict__ ridx, const float* __restrict__ aggin,
    float* __restrict__ aggout, int M, int N, int K, int bx, int by)
{
    constexpr int BK = 32;
    constexpr int PA = BM / 64;   // A staging passes (16B/thread each)
    constexpr int PB = BN / 64;
    constexpr int MI = BM / 32;   // per-wave 16-tiles in M
    constexpr int NJ = BN / 32;   // per-wave 16-tiles in N
    __shared__ bf16 As[BM * BK];
    __shared__ bf16 Bs[BN * BK];
    __shared__ int sIdx[BM];
    __shared__ int rIdx[BM];

    const int t = threadIdx.x;
    const int m0 = by * BM;
    const int n0 = bx * BN;

    if constexpr (AMODE == 3) {
        if (t < BM) {
            sIdx[t] = sidx[m0 + t] & (NODES - 1);   // OOB structurally impossible
            rIdx[t] = ridx[m0 + t] & (NODES - 1);
        }
        __syncthreads();
    }

    // staging: thread t covers LDS row (p*64 + t/4), 16B bf16 chunk (t%4)
    const int sr = t >> 2;
    const int sc = t & 3;

    uint4 ra[PA], rb[PB];

    auto loadTiles = [&](int kt) {
        const int kk = kt * BK + sc * 8;   // element column within K
#pragma unroll
        for (int p = 0; p < PA; ++p) {
            const int row = p * 64 + sr;
            if constexpr (AMODE == 0) {
                ra[p] = *(const uint4*)(A + (size_t)(m0 + row) * K + kk);
            } else if constexpr (AMODE == 1) {
                ra[p] = cvt8(Af + (size_t)(m0 + row) * K + kk);
            } else if constexpr (AMODE == 2) {
                const float* src = (kk < 256)
                    ? (inputsF + (size_t)(m0 + row) * 256 + kk)
                    : (aggin + (size_t)(m0 + row) * 256 + (kk - 256));
                ra[p] = cvt8(src);
            } else {
                const float4* u = (const float4*)(UV + (size_t)sIdx[row] * 1024 + kk);
                const float4* v = (const float4*)(UV + (size_t)rIdx[row] * 1024 + 512 + kk);
                const float4* c = (const float4*)(b1v + kk);
                float4 u0 = u[0], u1 = u[1], v0 = v[0], v1 = v[1], c0 = c[0], c1 = c[1];
                union { uint4 q; bf16 h[8]; } pk;
                pk.h[0] = __float2bfloat16(fmaxf(u0.x + v0.x + c0.x, 0.f));
                pk.h[1] = __float2bfloat16(fmaxf(u0.y + v0.y + c0.y, 0.f));
                pk.h[2] = __float2bfloat16(fmaxf(u0.z + v0.z + c0.z, 0.f));
                pk.h[3] = __float2bfloat16(fmaxf(u0.w + v0.w + c0.w, 0.f));
                pk.h[4] = __float2bfloat16(fmaxf(u1.x + v1.x + c1.x, 0.f));
                pk.h[5] = __float2bfloat16(fmaxf(u1.y + v1.y + c1.y, 0.f));
                pk.h[6] = __float2bfloat16(fmaxf(u1.z + v1.z + c1.z, 0.f));
                pk.h[7] = __float2bfloat16(fmaxf(u1.w + v1.w + c1.w, 0.f));
                ra[p] = pk.q;
            }
        }
#pragma unroll
        for (int p = 0; p < PB; ++p) {
            const int row = p * 64 + sr;
            if constexpr (BMODE == 0) {
                rb[p] = cvt8(Bt + (size_t)(n0 + row) * K + kk);
            } else {
                const int n = n0 + row;
                rb[p] = cvt8(Bt + (size_t)(n & 511) * 512 + (n >> 9) * 256 + kk);
            }
        }
    };

    const int wv = t >> 6;
    const int lane = t & 63;
    const int wm = wv >> 1, wn = wv & 1;   // wave covers (BM/2)x(BN/2)
    const int r16 = lane & 15, q = lane >> 4;

    floatx4 acc[MI][NJ] = {};

    loadTiles(0);
    const int KT = K / BK;
    for (int kt = 0; kt < KT; ++kt) {
        __syncthreads();
#pragma unroll
        for (int p = 0; p < PA; ++p)
            *(uint4*)(&As[(p * 64 + sr) * BK + sc * 8]) = ra[p];
#pragma unroll
        for (int p = 0; p < PB; ++p)
            *(uint4*)(&Bs[(p * 64 + sr) * BK + sc * 8]) = rb[p];
        __syncthreads();
        if (kt + 1 < KT) loadTiles(kt + 1);   // overlap next-tile loads with MFMA

        bf16x8 af[MI], bfr[NJ];
#pragma unroll
        for (int i = 0; i < MI; ++i)
            af[i] = *(const bf16x8*)(&As[(wm * (BM / 2) + i * 16 + r16) * BK + q * 8]);
#pragma unroll
        for (int j = 0; j < NJ; ++j)
            bfr[j] = *(const bf16x8*)(&Bs[(wn * (BN / 2) + j * 16 + r16) * BK + q * 8]);
#pragma unroll
        for (int i = 0; i < MI; ++i)
#pragma unroll
            for (int j = 0; j < NJ; ++j)
                acc[i][j] = __builtin_amdgcn_mfma_f32_16x16x32_bf16(af[i], bfr[j], acc[i][j], 0, 0, 0);
    }

    float bv[NJ];
#pragma unroll
    for (int j = 0; j < NJ; ++j)
        bv[j] = (EPI == 3) ? 0.f : bias[n0 + wn * (BN / 2) + j * 16 + r16];

    // C/D layout: col = lane&15, row = q*4 + r (verified m89/m91)
#pragma unroll
    for (int i = 0; i < MI; ++i) {
        const int lr = wm * (BM / 2) + i * 16 + q * 4;
        const int rbase = m0 + lr;
#pragma unroll
        for (int j = 0; j < NJ; ++j) {
            const int gc = n0 + wn * (BN / 2) + j * 16 + r16;
#pragma unroll
            for (int r = 0; r < 4; ++r) {
                float v = acc[i][j][r] + bv[j];
                const int gr = rbase + r;
                if constexpr (EPI == 0) {
                    v = fmaxf(v, 0.0f);
                    Cout[(size_t)gr * N + gc] = __float2bfloat16(v);
                } else if constexpr (EPI == 1) {
                    v = fmaxf(v, 0.0f);
                    atomicAdd(&aggout[(size_t)rIdx[lr + r] * 256 + gc], v);
                } else if constexpr (EPI == 2) {
                    OutF[(size_t)gr * 256 + gc] = inputsF[(size_t)gr * 256 + gc] + v;
                } else {
                    OutF[(size_t)gr * N + gc] = v;
                }
            }
        }
    }
}

template<int BM, int BN, int AMODE, int BMODE, int EPI>
__global__ __launch_bounds__(256, 2) void gemm_k(
    const bf16* __restrict__ A, const float* __restrict__ Af,
    const float* __restrict__ Bt, const float* __restrict__ bias,
    bf16* __restrict__ Cout, float* __restrict__ OutF,
    const float* __restrict__ inputsF, const float* __restrict__ UV,
    const float* __restrict__ b1v, const int* __restrict__ sidx,
    const int* __restrict__ ridx, const float* __restrict__ aggin,
    float* __restrict__ aggout, int M, int N, int K)
{
    gemm_body<BM, BN, AMODE, BMODE, EPI>(A, Af, Bt, bias, Cout, OutF, inputsF,
        UV, b1v, sidx, ridx, aggin, aggout, M, N, K, blockIdx.x, blockIdx.y);
}

// ---------------- fat front kernel: extract + zero + UV GEMM ---------------
// blocks [0,16384): one-hot index extraction (one wave per row, early exit)
// blocks [16384,16896): zero agg (2 MB)
// blocks [16896,17408): UV = inputs @ [W1_left|W1_right]^T (64x64 tiles)
__global__ __launch_bounds__(256) void fat_pre(
    const float* __restrict__ rel_rec, const float* __restrict__ rel_send,
    int* __restrict__ recv_idx, int* __restrict__ send_idx,
    float4* __restrict__ agg, const float* __restrict__ inputs,
    const float* __restrict__ msg_W1, float* __restrict__ UV)
{
    const int b = blockIdx.x;
    if (b < 16384) {
        const int half = b >> 13;          // 0: rel_rec, 1: rel_send
        const int rb = b & 8191;
        const float* mat = half ? rel_send : rel_rec;
        int* out = half ? send_idx : recv_idx;
        const int w = threadIdx.x >> 6;
        const int lane = threadIdx.x & 63;
        const int row = rb * 4 + w;        // 0..32767
        if (lane == 0) out[row] = 0;       // defensive init
        const uint4* base = (const uint4*)(mat + (size_t)row * NODES);
        for (int p = 0; p < 8; ++p) {
            uint4 v = base[p * 64 + lane];
            const bool hit = (v.x | v.y | v.z | v.w) != 0u;
            if (hit) {
                int e = v.x ? 0 : (v.y ? 1 : (v.z ? 2 : 3));
                out[row] = p * 256 + lane * 4 + e;
            }
            if (__any(hit)) break;         // wave early exit (avg ~4.5/8 passes)
        }
    } else if (b < 16896) {
        agg[(size_t)(b - 16384) * 256 + threadIdx.x] = float4{0.f, 0.f, 0.f, 0.f};
    } else {
        const int g = b - 16896;           // 512 blocks: 16 x-tiles, 32 y-tiles
        gemm_body<64, 64, 1, 1, 3>(nullptr, inputs, msg_W1, nullptr, nullptr, UV,
            nullptr, nullptr, nullptr, nullptr, nullptr, nullptr, nullptr,
            NODES, 1024, 256, g & 15, g >> 4);
    }
}

extern "C" void kernel_launch(void* const* d_in, const int* in_sizes, int n_in,
                              void* d_out, int out_size, void* d_ws, size_t ws_size,
                              hipStream_t stream) {
    const float* inputs   = (const float*)d_in[0];
    const float* rel_rec  = (const float*)d_in[1];
    const float* rel_send = (const float*)d_in[2];
    const float* msg_W1   = (const float*)d_in[3];
    const float* msg_b1   = (const float*)d_in[4];
    const float* msg_W2   = (const float*)d_in[5];
    const float* msg_b2   = (const float*)d_in[6];
    const float* out_W1   = (const float*)d_in[7];
    const float* out_b1   = (const float*)d_in[8];
    const float* out_W2   = (const float*)d_in[9];
    const float* out_b2   = (const float*)d_in[10];
    const float* out_W3   = (const float*)d_in[11];
    const float* out_b3   = (const float*)d_in[12];

    // workspace layout (~14.4 MB total)
    char* ws = (char*)d_ws;
    int*   recv_idx = (int*)(ws + 0);            // 128 KB
    int*   send_idx = (int*)(ws + 131072);       // 128 KB
    float* agg      = (float*)(ws + 262144);     // 2 MB fp32 [2048,256]
    float* UV       = (float*)(ws + 2359296);    // 8 MB fp32 [2048,1024] (U|V)
    bf16*  g1       = (bf16*)(ws + 10747904);    // 2 MB bf16 [2048,512]
    bf16*  g2       = (bf16*)(ws + 12845056);    // 2 MB bf16 [2048,512]
    if (ws_size < (size_t)16 * 1024 * 1024) return;  // fail loudly, not fault

    // 1) fused: index extraction + agg zeroing + UV GEMM (all independent)
    fat_pre<<<17408, 256, 0, stream>>>(rel_rec, rel_send, recv_idx, send_idx,
                                       (float4*)agg, inputs, msg_W1, UV);

    // 2) fused edge layer-2 + scatter (R4-best direct-atomic epilogue):
    //    agg[recv[e]] += relu( relu(U[send[e]]+V[recv[e]]+b1) @ W2^T + b2 )
    gemm_k<128, 128, 3, 0, 1><<<dim3(2, 256), 256, 0, stream>>>(
        nullptr, nullptr, msg_W2, msg_b2, nullptr, nullptr,
        nullptr, UV, msg_b1, send_idx, recv_idx, nullptr, agg,
        EDGES, 256, 512);

    // 3) node MLP layer 1 (64-tile, 256 blocks): g1 = relu(concat(inputs,agg)@W1^T+b1)
    gemm_k<64, 64, 2, 0, 0><<<dim3(8, 32), 256, 0, stream>>>(
        nullptr, nullptr, out_W1, out_b1, g1, nullptr,
        inputs, nullptr, nullptr, nullptr, nullptr, agg, nullptr,
        NODES, 512, 512);

    // 4) node MLP layer 2 (64-tile, 256 blocks): g2 = relu(g1 @ W2^T + b2)
    gemm_k<64, 64, 0, 0, 0><<<dim3(8, 32), 256, 0, stream>>>(
        g1, nullptr, out_W2, out_b2, g2, nullptr,
        nullptr, nullptr, nullptr, nullptr, nullptr, nullptr, nullptr,
        NODES, 512, 512);

    // 5) node MLP layer 3 + residual (64-tile, 128 blocks):
    //    out = inputs + (g2 @ W3^T + b3)
    gemm_k<64, 64, 0, 0, 2><<<dim3(4, 32), 256, 0, stream>>>(
        g2, nullptr, out_W3, out_b3, nullptr, (float*)d_out,
        inputs, nullptr, nullptr, nullptr, nullptr, nullptr, nullptr,
        NODES, 256, 512);
}